// Round 1
// baseline (1250.465 us; speedup 1.0000x reference)
//
#include <hip/hip_runtime.h>

typedef unsigned short u16;
typedef short short8 __attribute__((ext_vector_type(8)));
typedef float f32x4 __attribute__((ext_vector_type(4)));

#define T_SEQ 2048
#define D_EMB 1024

__device__ __forceinline__ u16 f2bf(float f) {
    union { float f; unsigned u; } c; c.f = f;
    unsigned r = c.u + 0x7fffu + ((c.u >> 16) & 1u);
    return (u16)(r >> 16);
}

__device__ __forceinline__ short8 ld_cvt8(const float* __restrict__ g) {
    float4 a = *reinterpret_cast<const float4*>(g);
    float4 b = *reinterpret_cast<const float4*>(g + 4);
    short8 v;
    v[0] = (short)f2bf(a.x); v[1] = (short)f2bf(a.y);
    v[2] = (short)f2bf(a.z); v[3] = (short)f2bf(a.w);
    v[4] = (short)f2bf(b.x); v[5] = (short)f2bf(b.y);
    v[6] = (short)f2bf(b.z); v[7] = (short)f2bf(b.w);
    return v;
}

// ---------------------------------------------------------------------------
// QKV projection: C[m,n] = sum_k X[m,k] * W[n,k]  (NT gemm, both K-contiguous)
// z = 0 -> Q [m][n], z = 1 -> K [m][n], z = 2 -> V stored transposed [b][h][t]
// 128x128 tile, BK=32, 4 waves, each wave 64x64 (4x4 tiles of 16x16x32 MFMA).
// ---------------------------------------------------------------------------
__global__ __launch_bounds__(256) void qkv_gemm(
    const float* __restrict__ X,
    const float* __restrict__ Wq,
    const float* __restrict__ Wk,
    const float* __restrict__ Wv,
    u16* __restrict__ Qo,
    u16* __restrict__ Ko,
    u16* __restrict__ VTo)
{
    __shared__ u16 As[128 * 32];
    __shared__ u16 Bs[128 * 32];

    const int tid  = threadIdx.x;
    const int lane = tid & 63;
    const int w    = tid >> 6;
    const int wm   = w >> 1, wn = w & 1;
    const int kg   = lane >> 4;
    const int l15  = lane & 15;

    const int m0 = blockIdx.x * 128;
    const int n0 = blockIdx.y * 128;
    const int z  = blockIdx.z;
    const float* Wz = (z == 0) ? Wq : (z == 1) ? Wk : Wv;

    const f32x4 z4 = {0.f, 0.f, 0.f, 0.f};
    f32x4 acc[4][4];
    #pragma unroll
    for (int i = 0; i < 4; ++i)
        #pragma unroll
        for (int j = 0; j < 4; ++j) acc[i][j] = z4;

    // staging: each thread moves 2x16B for A and for B per K-step
    const int srow0 = w * 16 + (lane >> 2);   // rows 0..63
    const int srow1 = srow0 + 64;             // rows 64..127
    const int skk   = (lane & 3) * 8;
    const int soff0 = srow0 * 32 + skk;
    const int soff1 = srow1 * 32 + skk;

    for (int k0 = 0; k0 < 1024; k0 += 32) {
        short8 a0 = ld_cvt8(X  + (size_t)(m0 + srow0) * 1024 + k0 + skk);
        short8 a1 = ld_cvt8(X  + (size_t)(m0 + srow1) * 1024 + k0 + skk);
        short8 b0 = ld_cvt8(Wz + (size_t)(n0 + srow0) * 1024 + k0 + skk);
        short8 b1 = ld_cvt8(Wz + (size_t)(n0 + srow1) * 1024 + k0 + skk);
        __syncthreads();                // previous iter's LDS reads complete
        *reinterpret_cast<short8*>(&As[soff0]) = a0;
        *reinterpret_cast<short8*>(&As[soff1]) = a1;
        *reinterpret_cast<short8*>(&Bs[soff0]) = b0;
        *reinterpret_cast<short8*>(&Bs[soff1]) = b1;
        __syncthreads();

        short8 af[4], bv[4];
        #pragma unroll
        for (int mt = 0; mt < 4; ++mt)
            af[mt] = *reinterpret_cast<const short8*>(&As[(wm * 64 + mt * 16 + l15) * 32 + kg * 8]);
        #pragma unroll
        for (int nt = 0; nt < 4; ++nt)
            bv[nt] = *reinterpret_cast<const short8*>(&Bs[(wn * 64 + nt * 16 + l15) * 32 + kg * 8]);
        #pragma unroll
        for (int mt = 0; mt < 4; ++mt)
            #pragma unroll
            for (int nt = 0; nt < 4; ++nt)
                acc[mt][nt] = __builtin_amdgcn_mfma_f32_16x16x32_bf16(af[mt], bv[nt], acc[mt][nt], 0, 0, 0);
    }

    // C/D fragment: col = lane&15, row = (lane>>4)*4 + r   [m89 verified]
    if (z < 2) {
        u16* O = (z == 0) ? Qo : Ko;
        #pragma unroll
        for (int mt = 0; mt < 4; ++mt) {
            const int row0 = m0 + wm * 64 + mt * 16 + kg * 4;
            #pragma unroll
            for (int nt = 0; nt < 4; ++nt) {
                const int col = n0 + wn * 64 + nt * 16 + l15;
                #pragma unroll
                for (int r = 0; r < 4; ++r)
                    O[(size_t)(row0 + r) * 1024 + col] = f2bf(acc[mt][nt][r]);
            }
        }
    } else {
        #pragma unroll
        for (int mt = 0; mt < 4; ++mt) {
            const int row0 = m0 + wm * 64 + mt * 16 + kg * 4;
            #pragma unroll
            for (int nt = 0; nt < 4; ++nt) {
                const int col = n0 + wn * 64 + nt * 16 + l15;   // h
                #pragma unroll
                for (int r = 0; r < 4; ++r) {
                    const int rr = row0 + r;
                    const int bb = rr >> 11;       // /2048
                    const int tt = rr & 2047;
                    VTo[((size_t)bb * 1024 + col) * 2048 + tt] = f2bf(acc[mt][nt][r]);
                }
            }
        }
    }
}

// ---------------------------------------------------------------------------
// Fused causal attention. One WG per (b, 16-row query block), 8 waves.
// S phase: waves split key tiles (16 keys each), S kept in registers.
// Online softmax across key chunks of 1024; unnormalized P (bf16) in LDS.
// PV phase: wave w owns h in [w*128, w*128+128), reads V^T (16B/lane).
// ---------------------------------------------------------------------------
__global__ __launch_bounds__(512) void attn_fused(
    const u16* __restrict__ Q,    // [8*2048][1024] bf16
    const u16* __restrict__ K,    // [8*2048][1024] bf16
    const u16* __restrict__ VT,   // [8][1024][2048] bf16
    float* __restrict__ Out)      // [8*2048][1024] f32
{
    __shared__ u16 Plds[16][1032];   // +8 pad: 2-way (free) bank pattern
    __shared__ float redm[8][16];
    __shared__ float reds[8][16];

    const int tid  = threadIdx.x;
    const int lane = tid & 63;
    const int w    = tid >> 6;
    const int kg   = lane >> 4;
    const int l15  = lane & 15;
    const int qb = blockIdx.x;
    const int b  = blockIdx.y;
    const int nt = qb + 1;          // key tiles (16 keys each)
    const int t0 = qb * 16;

    const f32x4 z4 = {0.f, 0.f, 0.f, 0.f};
    const f32x4 n4 = {-1e30f, -1e30f, -1e30f, -1e30f};

    float m_run[4], s_run[4];
    #pragma unroll
    for (int r = 0; r < 4; ++r) { m_run[r] = -1e30f; s_run[r] = 0.f; }
    f32x4 oacc[8];
    #pragma unroll
    for (int i = 0; i < 8; ++i) oacc[i] = z4;

    const u16* qbase = Q + ((size_t)(b * T_SEQ + t0 + l15)) * 1024 + kg * 8;

    for (int c = 0; c * 64 < nt; ++c) {
        const int jbeg = c * 64;
        const int ntc  = min(nt - jbeg, 64);   // tiles in this chunk

        // ---- S = Q K^T (this chunk), kept in registers ----
        f32x4 sreg[8];
        float pmax[4];
        #pragma unroll
        for (int r = 0; r < 4; ++r) pmax[r] = -1e30f;

        #pragma unroll
        for (int jj = 0; jj < 8; ++jj) {
            const int jl = w + jj * 8;
            if (jl < ntc) {
                const int j = jbeg + jl;
                f32x4 acc = z4;
                const u16* kbase = K + ((size_t)(b * T_SEQ + j * 16 + l15)) * 1024 + kg * 8;
                #pragma unroll
                for (int ks = 0; ks < 32; ++ks) {
                    short8 a  = *reinterpret_cast<const short8*>(qbase + ks * 32);
                    short8 bb = *reinterpret_cast<const short8*>(kbase + ks * 32);
                    acc = __builtin_amdgcn_mfma_f32_16x16x32_bf16(a, bb, acc, 0, 0, 0);
                }
                #pragma unroll
                for (int r = 0; r < 4; ++r) {
                    float sv = acc[r] * 0.03125f;          // scale = EMB^-0.5
                    const int qr = kg * 4 + r;             // query row in block
                    const int sc = j * 16 + l15;           // absolute key idx
                    sv = (sc <= t0 + qr) ? sv : -1e30f;    // causal mask
                    acc[r] = sv;
                    pmax[r] = fmaxf(pmax[r], sv);
                }
                sreg[jj] = acc;
            } else {
                sreg[jj] = n4;
            }
        }

        // ---- row max: 16-lane butterfly, then cross-wave via LDS ----
        #pragma unroll
        for (int r = 0; r < 4; ++r)
            #pragma unroll
            for (int d = 1; d < 16; d <<= 1)
                pmax[r] = fmaxf(pmax[r], __shfl_xor(pmax[r], d, 64));
        if (l15 == 0) {
            #pragma unroll
            for (int r = 0; r < 4; ++r) redm[w][kg * 4 + r] = pmax[r];
        }
        __syncthreads();   // redm ready; also: prev chunk's PV reads of Plds done

        float mnew[4], fac[4];
        #pragma unroll
        for (int r = 0; r < 4; ++r) {
            float m = -1e30f;
            #pragma unroll
            for (int ww = 0; ww < 8; ++ww) m = fmaxf(m, redm[ww][kg * 4 + r]);
            mnew[r]  = fmaxf(m_run[r], m);
            fac[r]   = __expf(m_run[r] - mnew[r]);
            m_run[r] = mnew[r];
        }

        // ---- P = exp(S - m), unnormalized, bf16 -> LDS; partial sums ----
        float psum[4] = {0.f, 0.f, 0.f, 0.f};
        #pragma unroll
        for (int jj = 0; jj < 8; ++jj) {
            const int jl = w + jj * 8;
            if (jl < ntc) {
                #pragma unroll
                for (int r = 0; r < 4; ++r) {
                    float p = __expf(sreg[jj][r] - mnew[r]);
                    psum[r] += p;
                    Plds[kg * 4 + r][jl * 16 + l15] = f2bf(p);
                }
            }
        }
        #pragma unroll
        for (int r = 0; r < 4; ++r)
            #pragma unroll
            for (int d = 1; d < 16; d <<= 1)
                psum[r] += __shfl_xor(psum[r], d, 64);
        if (l15 == 0) {
            #pragma unroll
            for (int r = 0; r < 4; ++r) reds[w][kg * 4 + r] = psum[r];
        }
        if (ntc & 1) {   // zero-pad P to a multiple of 32 keys for the MFMA
            if (tid < 256) Plds[tid >> 4][ntc * 16 + (tid & 15)] = 0;
        }
        __syncthreads();  // P + reds ready

        #pragma unroll
        for (int r = 0; r < 4; ++r) {
            float s = 0.f;
            #pragma unroll
            for (int ww = 0; ww < 8; ++ww) s += reds[ww][kg * 4 + r];
            s_run[r] = s_run[r] * fac[r] + s;
        }
        #pragma unroll
        for (int ht = 0; ht < 8; ++ht)
            #pragma unroll
            for (int r = 0; r < 4; ++r)
                oacc[ht][r] *= fac[r];

        // ---- O += P * V (wave owns 128-wide h slice) ----
        const int nkc = (ntc + 1) >> 1;   // 32-key MFMA k-steps
        const int hb = w * 128;
        for (int kk = 0; kk < nkc; ++kk) {
            const short8 pa = *reinterpret_cast<const short8*>(&Plds[l15][kk * 32 + kg * 8]);
            const int sbase = jbeg * 16 + kk * 32 + kg * 8;
            #pragma unroll
            for (int ht = 0; ht < 8; ++ht) {
                const u16* vp = VT + ((size_t)(b * 1024 + hb + ht * 16 + l15)) * 2048 + sbase;
                short8 bv = *reinterpret_cast<const short8*>(vp);
                oacc[ht] = __builtin_amdgcn_mfma_f32_16x16x32_bf16(pa, bv, oacc[ht], 0, 0, 0);
            }
        }
        // next chunk's first __syncthreads() protects Plds before overwrite
    }

    // ---- epilogue: normalize and store f32 ----
    const int hb = w * 128;
    #pragma unroll
    for (int r = 0; r < 4; ++r) {
        const float rinv = 1.0f / s_run[r];
        const int t = t0 + kg * 4 + r;
        float* orow = Out + ((size_t)(b * T_SEQ + t)) * 1024;
        #pragma unroll
        for (int ht = 0; ht < 8; ++ht)
            orow[hb + ht * 16 + l15] = oacc[ht][r] * rinv;
    }
}

extern "C" void kernel_launch(void* const* d_in, const int* in_sizes, int n_in,
                              void* d_out, int out_size, void* d_ws, size_t ws_size,
                              hipStream_t stream) {
    const float* x  = (const float*)d_in[0];
    const float* Wq = (const float*)d_in[1];
    const float* Wk = (const float*)d_in[2];
    const float* Wv = (const float*)d_in[3];
    float* out = (float*)d_out;

    // workspace: Q, K (bf16 [16384][1024]) and V^T (bf16 [8][1024][2048]) = ~100.7 MB
    u16* Qb  = (u16*)d_ws;
    u16* Kb  = Qb + (size_t)16384 * 1024;
    u16* VTb = Kb + (size_t)16384 * 1024;

    qkv_gemm<<<dim3(128, 8, 3), 256, 0, stream>>>(x, Wq, Wk, Wv, Qb, Kb, VTb);
    attn_fused<<<dim3(128, 8), 512, 0, stream>>>(Qb, Kb, VTb, out);
}

// Round 2
// 376.033 us; speedup vs baseline: 3.3254x; 3.3254x over previous
//
#include <hip/hip_runtime.h>

typedef unsigned short u16;
typedef short short8 __attribute__((ext_vector_type(8)));
typedef float f32x4 __attribute__((ext_vector_type(4)));

#define NROW 16384           // B*T
#define EMBD 1024

__device__ __forceinline__ u16 f2bf(float f) {
    union { float f; unsigned u; } c; c.f = f;
    unsigned r = c.u + 0x7fffu + ((c.u >> 16) & 1u);
    return (u16)(r >> 16);
}
__device__ __forceinline__ float bf2f(u16 h) {
    union { unsigned u; float f; } c; c.u = ((unsigned)h) << 16; return c.f;
}

// async global->LDS, 16B per lane. LDS dest is wave-uniform base + lane*16.
__device__ __forceinline__ void gll16(const u16* g, u16* l) {
    __builtin_amdgcn_global_load_lds(
        (const __attribute__((address_space(1))) void*)g,
        (__attribute__((address_space(3))) void*)l, 16, 0, 0);
}

// ---------------------------------------------------------------------------
// Shared NT-GEMM mainloop: acc += A[m0+.. , k] * B[n0+.. , k], K-contiguous
// bf16 operands. 128x128 tile, BK=32, 4 waves, wave tile 64x64 (4x4 MFMA).
// As/Bs are [128*32] u16 LDS tiles. m97 2-barrier structure, global_load_lds.
// ---------------------------------------------------------------------------
__device__ __forceinline__ void gemm_mainloop(
    const u16* __restrict__ A, int lda,
    const u16* __restrict__ B, int ldb,
    int m0, int n0, int kN,
    u16* As, u16* Bs, int tid, f32x4 acc[4][4])
{
    const int lane = tid & 63;
    const int w    = tid >> 6;
    const int wm   = w >> 1, wn = w & 1;
    const int kg   = lane >> 4;
    const int l15  = lane & 15;
    const int grow = w * 16 + (lane >> 2);   // staging row 0..63
    const int gk8  = (lane & 3) * 8;         // staging k-offset

    const u16* Ap0 = A + (size_t)(m0 + grow)      * lda + gk8;
    const u16* Ap1 = A + (size_t)(m0 + grow + 64) * lda + gk8;
    const u16* Bp0 = B + (size_t)(n0 + grow)      * ldb + gk8;
    const u16* Bp1 = B + (size_t)(n0 + grow + 64) * ldb + gk8;
    u16* Asw = As + w * (16 * 32);
    u16* Bsw = Bs + w * (16 * 32);

    for (int k0 = 0; k0 < kN; k0 += 32) {
        __syncthreads();                     // prev iter's ds_reads complete
        gll16(Ap0 + k0, Asw);
        gll16(Ap1 + k0, Asw + 64 * 32);
        gll16(Bp0 + k0, Bsw);
        gll16(Bp1 + k0, Bsw + 64 * 32);
        __syncthreads();                     // compiler drains vmcnt(0) here

        short8 af[4], bf[4];
        #pragma unroll
        for (int mt = 0; mt < 4; ++mt)
            af[mt] = *reinterpret_cast<const short8*>(&As[(wm * 64 + mt * 16 + l15) * 32 + kg * 8]);
        #pragma unroll
        for (int nt = 0; nt < 4; ++nt)
            bf[nt] = *reinterpret_cast<const short8*>(&Bs[(wn * 64 + nt * 16 + l15) * 32 + kg * 8]);
        #pragma unroll
        for (int mt = 0; mt < 4; ++mt)
            #pragma unroll
            for (int nt = 0; nt < 4; ++nt)
                acc[mt][nt] = __builtin_amdgcn_mfma_f32_16x16x32_bf16(af[mt], bf[nt], acc[mt][nt], 0, 0, 0);
    }
}

// ---------------------------------------------------------------------------
// 0) cast x and Wq/Wk/Wv to bf16 into d_out: xb[16M] then Wb[3][1M]
// ---------------------------------------------------------------------------
__global__ __launch_bounds__(256) void cvt_bf16(
    const float* __restrict__ x,
    const float* __restrict__ Wq,
    const float* __restrict__ Wk,
    const float* __restrict__ Wv,
    u16* __restrict__ dst)
{
    const size_t e = ((size_t)blockIdx.x * 256 + threadIdx.x) * 8;
    const float* src;
    if (e < (size_t)16777216) {
        src = x + e;
    } else {
        size_t j = e - 16777216;
        int z = (int)(j >> 20);
        const float* Wz = (z == 0) ? Wq : (z == 1) ? Wk : Wv;
        src = Wz + (j & 1048575);
    }
    float4 a = *reinterpret_cast<const float4*>(src);
    float4 b = *reinterpret_cast<const float4*>(src + 4);
    short8 v;
    v[0] = (short)f2bf(a.x); v[1] = (short)f2bf(a.y);
    v[2] = (short)f2bf(a.z); v[3] = (short)f2bf(a.w);
    v[4] = (short)f2bf(b.x); v[5] = (short)f2bf(b.y);
    v[6] = (short)f2bf(b.z); v[7] = (short)f2bf(b.w);
    *reinterpret_cast<short8*>(dst + e) = v;
}

// ---------------------------------------------------------------------------
// 1) QKV projection (bf16 in, bf16 out). z=0 Q, z=1 K, z=2 V^T [b][h][t]
// ---------------------------------------------------------------------------
__global__ __launch_bounds__(256) void qkv_bf16(
    const u16* __restrict__ xb,   // [16384][1024]
    const u16* __restrict__ Wb,   // [3][1024][1024]
    u16* __restrict__ Qo, u16* __restrict__ Ko, u16* __restrict__ VTo)
{
    __shared__ u16 As[128 * 32];
    __shared__ u16 Bs[128 * 32];
    const int tid = threadIdx.x;
    const int lane = tid & 63, w = tid >> 6;
    const int wm = w >> 1, wn = w & 1, kg = lane >> 4, l15 = lane & 15;
    const int m0 = blockIdx.x * 128, n0 = blockIdx.y * 128, z = blockIdx.z;

    const f32x4 z4 = {0.f, 0.f, 0.f, 0.f};
    f32x4 acc[4][4];
    #pragma unroll
    for (int i = 0; i < 4; ++i)
        #pragma unroll
        for (int j = 0; j < 4; ++j) acc[i][j] = z4;

    gemm_mainloop(xb, 1024, Wb + (size_t)z * 1048576, 1024, m0, n0, 1024, As, Bs, tid, acc);

    if (z < 2) {
        u16* O = (z == 0) ? Qo : Ko;
        #pragma unroll
        for (int mt = 0; mt < 4; ++mt) {
            const int row0 = m0 + wm * 64 + mt * 16 + kg * 4;
            #pragma unroll
            for (int nt = 0; nt < 4; ++nt) {
                const int col = n0 + wn * 64 + nt * 16 + l15;
                #pragma unroll
                for (int r = 0; r < 4; ++r)
                    O[(size_t)(row0 + r) * 1024 + col] = f2bf(acc[mt][nt][r]);
            }
        }
    } else {
        #pragma unroll
        for (int mt = 0; mt < 4; ++mt) {
            const int row0 = m0 + wm * 64 + mt * 16 + kg * 4;
            #pragma unroll
            for (int nt = 0; nt < 4; ++nt) {
                const int col = n0 + wn * 64 + nt * 16 + l15;   // h
                #pragma unroll
                for (int r = 0; r < 4; ++r) {
                    const int rr = row0 + r;
                    VTo[((size_t)(rr >> 11) * 1024 + col) * 2048 + (rr & 2047)] = f2bf(acc[mt][nt][r]);
                }
            }
        }
    }
}

// ---------------------------------------------------------------------------
// 2) S = Q K^T (causal blocks only), epilogue P = exp(S/32) masked, bf16
// grid (qblk 16, kblk 16, b 8); P[b][t][s] in d_out
// ---------------------------------------------------------------------------
__global__ __launch_bounds__(256) void sp_gemm(
    const u16* __restrict__ Q, const u16* __restrict__ K, u16* __restrict__ P)
{
    const int qblk = blockIdx.x, kblk = blockIdx.y, b = blockIdx.z;
    if (kblk > qblk) return;
    __shared__ u16 As[128 * 32];
    __shared__ u16 Bs[128 * 32];
    const int tid = threadIdx.x;
    const int lane = tid & 63, w = tid >> 6;
    const int wm = w >> 1, wn = w & 1, kg = lane >> 4, l15 = lane & 15;

    const f32x4 z4 = {0.f, 0.f, 0.f, 0.f};
    f32x4 acc[4][4];
    #pragma unroll
    for (int i = 0; i < 4; ++i)
        #pragma unroll
        for (int j = 0; j < 4; ++j) acc[i][j] = z4;

    gemm_mainloop(Q, 1024, K, 1024, b * 2048 + qblk * 128, b * 2048 + kblk * 128,
                  1024, As, Bs, tid, acc);

    u16* Pb = P + (size_t)b * 2048 * 2048;
    #pragma unroll
    for (int mt = 0; mt < 4; ++mt) {
        const int trow0 = qblk * 128 + wm * 64 + mt * 16 + kg * 4;
        #pragma unroll
        for (int nt = 0; nt < 4; ++nt) {
            const int scol = kblk * 128 + wn * 64 + nt * 16 + l15;
            #pragma unroll
            for (int r = 0; r < 4; ++r) {
                const int trow = trow0 + r;
                const float p = (scol <= trow) ? __expf(acc[mt][nt][r] * 0.03125f) : 0.f;
                Pb[(size_t)trow * 2048 + scol] = f2bf(p);
            }
        }
    }
}

// ---------------------------------------------------------------------------
// 3) O = P * V^T (unnormalized, f32) -> Of.  grid (b*16+qblk, hpanel 8)
// ---------------------------------------------------------------------------
__global__ __launch_bounds__(256) void pv_gemm(
    const u16* __restrict__ P, const u16* __restrict__ VT, float* __restrict__ Of)
{
    const int mb = blockIdx.x;            // b*16 + qblk
    const int nb = blockIdx.y;            // h panel
    const int b = mb >> 4, qblk = mb & 15;
    const int kN = (qblk + 1) * 128;
    __shared__ u16 As[128 * 32];
    __shared__ u16 Bs[128 * 32];
    const int tid = threadIdx.x;
    const int lane = tid & 63, w = tid >> 6;
    const int wm = w >> 1, wn = w & 1, kg = lane >> 4, l15 = lane & 15;

    const f32x4 z4 = {0.f, 0.f, 0.f, 0.f};
    f32x4 acc[4][4];
    #pragma unroll
    for (int i = 0; i < 4; ++i)
        #pragma unroll
        for (int j = 0; j < 4; ++j) acc[i][j] = z4;

    gemm_mainloop(P + (size_t)b * 2048 * 2048, 2048,
                  VT + (size_t)b * 1024 * 2048, 2048,
                  qblk * 128, nb * 128, kN, As, Bs, tid, acc);

    #pragma unroll
    for (int mt = 0; mt < 4; ++mt) {
        const int trow0 = qblk * 128 + wm * 64 + mt * 16 + kg * 4;
        #pragma unroll
        for (int nt = 0; nt < 4; ++nt) {
            const int col = nb * 128 + wn * 64 + nt * 16 + l15;
            #pragma unroll
            for (int r = 0; r < 4; ++r)
                Of[((size_t)b * 2048 + trow0 + r) * 1024 + col] = acc[mt][nt][r];
        }
    }
}

// ---------------------------------------------------------------------------
// 4) per row: l = sum(P row), out = Of / l.  One block per row; reads and
// writes only its own row's bytes (P row and out row alias exactly).
// ---------------------------------------------------------------------------
__global__ __launch_bounds__(256) void finalize(
    const u16* __restrict__ P, const float* __restrict__ Of, float* __restrict__ out)
{
    const int row = blockIdx.x;           // 0..16383
    const int tid = threadIdx.x;
    const int b = row >> 11, t = row & 2047;
    const int len = ((t >> 7) + 1) * 128;
    const u16* prow = P + ((size_t)b * 2048 + t) * 2048;

    float s = 0.f;
    const int i = tid * 8;
    if (i < len) {
        short8 v = *reinterpret_cast<const short8*>(prow + i);
        #pragma unroll
        for (int j = 0; j < 8; ++j) s += bf2f((u16)v[j]);
    }
    #pragma unroll
    for (int d = 1; d < 64; d <<= 1) s += __shfl_xor(s, d, 64);

    __shared__ float red[4];
    if ((tid & 63) == 0) red[tid >> 6] = s;
    __syncthreads();
    const float rinv = 1.f / (red[0] + red[1] + red[2] + red[3]);

    const size_t o = (size_t)row * 1024 + tid * 4;
    f32x4 v = *reinterpret_cast<const f32x4*>(Of + o);
    v[0] *= rinv; v[1] *= rinv; v[2] *= rinv; v[3] *= rinv;
    *reinterpret_cast<f32x4*>(out + o) = v;
}

extern "C" void kernel_launch(void* const* d_in, const int* in_sizes, int n_in,
                              void* d_out, int out_size, void* d_ws, size_t ws_size,
                              hipStream_t stream) {
    const float* x  = (const float*)d_in[0];
    const float* Wq = (const float*)d_in[1];
    const float* Wk = (const float*)d_in[2];
    const float* Wv = (const float*)d_in[3];
    float* out = (float*)d_out;

    // ws: Q[16384][1024] | K[16384][1024] | VT[8][1024][2048]  (96 MiB bf16)
    u16* Qb  = (u16*)d_ws;
    u16* Kb  = Qb + (size_t)16384 * 1024;
    u16* VTb = Kb + (size_t)16384 * 1024;
    float* Of = (float*)d_ws;              // overlays Q,K (dead after sp_gemm)

    // d_out overlays: phase A = xb[16M] + Wb[3M] bf16; phase B = P bf16; final = out f32
    u16* xb = (u16*)d_out;
    u16* Wb = xb + (size_t)16777216;
    u16* Pb = (u16*)d_out;

    cvt_bf16<<<dim3(9728), 256, 0, stream>>>(x, Wq, Wk, Wv, xb);
    qkv_bf16<<<dim3(128, 8, 3), 256, 0, stream>>>(xb, Wb, Qb, Kb, VTb);
    sp_gemm<<<dim3(16, 16, 8), 256, 0, stream>>>(Qb, Kb, Pb);
    pv_gemm<<<dim3(128, 8), 256, 0, stream>>>(Pb, VTb, Of);
    finalize<<<dim3(16384), 256, 0, stream>>>(Pb, Of, out);
}

// Round 3
// 299.790 us; speedup vs baseline: 4.1711x; 1.2543x over previous
//
#include <hip/hip_runtime.h>

typedef unsigned short u16;
typedef short short8 __attribute__((ext_vector_type(8)));
typedef float f32x4 __attribute__((ext_vector_type(4)));

__device__ __forceinline__ u16 f2bf(float f) {
    union { float f; unsigned u; } c; c.f = f;
    unsigned r = c.u + 0x7fffu + ((c.u >> 16) & 1u);
    return (u16)(r >> 16);
}
__device__ __forceinline__ float bf2f(u16 h) {
    union { unsigned u; float f; } c; c.u = ((unsigned)h) << 16; return c.f;
}

// async global->LDS, 16B/lane; LDS dest = wave-uniform base + lane*16
__device__ __forceinline__ void gll16(const u16* g, u16* l) {
    __builtin_amdgcn_global_load_lds(
        (const __attribute__((address_space(1))) void*)g,
        (__attribute__((address_space(3))) void*)l, 16, 0, 0);
}

// Stage one half-tile (128 rows x 64 k, 16 KB) into LDS, linear dest,
// pre-swizzled global source: LDS slot s holds global k-slot s^(row&7).
__device__ __forceinline__ void stage_half(const u16* __restrict__ g, int ld,
                                           u16* lds, int w, int lane) {
    int rowl = w * 16 + (lane >> 3);
    int s = lane & 7;
    gll16(g + (size_t)rowl * ld + ((s ^ (rowl & 7)) << 3), lds + (w * 2) * 512);
    rowl += 8;
    gll16(g + (size_t)rowl * ld + ((s ^ (rowl & 7)) << 3), lds + (w * 2 + 1) * 512);
}

// read a 16B fragment: byte = row*128 + ((slot ^ (row&7))*16)
__device__ __forceinline__ short8 ldsfrag(const u16* h, int row, int slot) {
    return *reinterpret_cast<const short8*>(h + row * 64 + ((slot ^ (row & 7)) << 3));
}

// ---------------------------------------------------------------------------
// 256x256 NT-GEMM mainloop, BK=64, 8 waves (2Mx4N), counted-vmcnt schedule.
// A of tile t lives in Ab[(t&1)*2+half], B of tile t in Bb[(t&1)*2+half].
// Per tile: 4 phases; ph0/ph1 stage (t+1).A, ph2/ph3 stage (t+2).B into the
// region freed at this tile's ph0. End-of-tile s_waitcnt vmcnt(4) (never 0
// until the tail) placed BEFORE the barrier => block-wide guarantee.
// ---------------------------------------------------------------------------
__device__ __forceinline__ void gemm256(
    const u16* __restrict__ A, int lda,
    const u16* __restrict__ B, int ldb,
    int m0, int n0, int nk,
    u16* Ab, u16* Bb, f32x4 acc[8][4])
{
    const int tid  = threadIdx.x;
    const int lane = tid & 63;
    const int w    = tid >> 6;
    const int wm   = w >> 2;          // 0..1
    const int wn   = w & 3;           // 0..3
    const int kg   = lane >> 4, l15 = lane & 15;

    const u16* Am = A + (size_t)m0 * lda;
    const u16* Bn = B + (size_t)n0 * ldb;

    // prologue: t0.{A0,A1,B0,B1}, t1.{B0,B1}
    stage_half(Am,                       lda, Ab + 0 * 8192, w, lane);
    stage_half(Am + (size_t)128 * lda,   lda, Ab + 1 * 8192, w, lane);
    stage_half(Bn,                       ldb, Bb + 0 * 8192, w, lane);
    stage_half(Bn + (size_t)128 * ldb,   ldb, Bb + 1 * 8192, w, lane);
    if (nk > 1) {
        stage_half(Bn + 64,                     ldb, Bb + 2 * 8192, w, lane);
        stage_half(Bn + (size_t)128 * ldb + 64, ldb, Bb + 3 * 8192, w, lane);
        asm volatile("s_waitcnt vmcnt(4)" ::: "memory");
    } else {
        asm volatile("s_waitcnt vmcnt(0)" ::: "memory");
    }
    __builtin_amdgcn_s_barrier();

    for (int t = 0; t < nk; ++t) {
        const int p = t & 1;
        const u16* Ahalf = Ab + (p * 2 + wm) * 8192;
        const u16* Bhalf = Bb + (p * 2 + (wn >> 1)) * 8192;
        const int brow0 = (wn & 1) * 64;
        short8 bfr[4][2];

        #pragma unroll
        for (int mp = 0; mp < 4; ++mp) {
            short8 a[2][2];
            #pragma unroll
            for (int mi = 0; mi < 2; ++mi)
                #pragma unroll
                for (int ks = 0; ks < 2; ++ks)
                    a[mi][ks] = ldsfrag(Ahalf, (mp * 2 + mi) * 16 + l15, ks * 4 + kg);
            if (mp == 0) {
                #pragma unroll
                for (int nt = 0; nt < 4; ++nt)
                    #pragma unroll
                    for (int ks = 0; ks < 2; ++ks)
                        bfr[nt][ks] = ldsfrag(Bhalf, brow0 + nt * 16 + l15, ks * 4 + kg);
            }
            // prefetch staging (A one tile ahead, B two tiles ahead)
            if (mp == 0 && t + 1 < nk)
                stage_half(Am + (t + 1) * 64, lda, Ab + ((p ^ 1) * 2 + 0) * 8192, w, lane);
            if (mp == 1 && t + 1 < nk)
                stage_half(Am + (size_t)128 * lda + (t + 1) * 64, lda, Ab + ((p ^ 1) * 2 + 1) * 8192, w, lane);
            if (mp == 2 && t + 2 < nk)
                stage_half(Bn + (t + 2) * 64, ldb, Bb + (p * 2 + 0) * 8192, w, lane);
            if (mp == 3 && t + 2 < nk)
                stage_half(Bn + (size_t)128 * ldb + (t + 2) * 64, ldb, Bb + (p * 2 + 1) * 8192, w, lane);

            __builtin_amdgcn_s_barrier();
            __builtin_amdgcn_s_setprio(1);
            #pragma unroll
            for (int ks = 0; ks < 2; ++ks)
                #pragma unroll
                for (int mi = 0; mi < 2; ++mi)
                    #pragma unroll
                    for (int nt = 0; nt < 4; ++nt)
                        acc[mp * 2 + mi][nt] = __builtin_amdgcn_mfma_f32_16x16x32_bf16(
                            a[mi][ks], bfr[nt][ks], acc[mp * 2 + mi][nt], 0, 0, 0);
            __builtin_amdgcn_s_setprio(0);
            if (mp == 3) {
                if (t + 2 < nk) asm volatile("s_waitcnt vmcnt(4)" ::: "memory");
                else            asm volatile("s_waitcnt vmcnt(0)" ::: "memory");
            }
            __builtin_amdgcn_s_barrier();
        }
    }
}

// ---------------------------------------------------------------------------
// 0) cast x and Wq/Wk/Wv to bf16 into d_out: xb[16M] then Wb[3][1M]
// ---------------------------------------------------------------------------
__global__ __launch_bounds__(256) void cvt_bf16(
    const float* __restrict__ x,
    const float* __restrict__ Wq,
    const float* __restrict__ Wk,
    const float* __restrict__ Wv,
    u16* __restrict__ dst)
{
    const size_t e = ((size_t)blockIdx.x * 256 + threadIdx.x) * 8;
    const float* src;
    if (e < (size_t)16777216) {
        src = x + e;
    } else {
        size_t j = e - 16777216;
        int z = (int)(j >> 20);
        const float* Wz = (z == 0) ? Wq : (z == 1) ? Wk : Wv;
        src = Wz + (j & 1048575);
    }
    float4 a = *reinterpret_cast<const float4*>(src);
    float4 b = *reinterpret_cast<const float4*>(src + 4);
    short8 v;
    v[0] = (short)f2bf(a.x); v[1] = (short)f2bf(a.y);
    v[2] = (short)f2bf(a.z); v[3] = (short)f2bf(a.w);
    v[4] = (short)f2bf(b.x); v[5] = (short)f2bf(b.y);
    v[6] = (short)f2bf(b.z); v[7] = (short)f2bf(b.w);
    *reinterpret_cast<short8*>(dst + e) = v;
}

// ---------------------------------------------------------------------------
// 1) QKV projection. z=0 Q, z=1 K, z=2 V^T [b][h][t]
// ---------------------------------------------------------------------------
__global__ __launch_bounds__(512, 2) void qkv256(
    const u16* __restrict__ xb,   // [16384][1024]
    const u16* __restrict__ Wb,   // [3][1024][1024]
    u16* __restrict__ Qo, u16* __restrict__ Ko, u16* __restrict__ VTo)
{
    __shared__ u16 Ab[4][8192];
    __shared__ u16 Bb[4][8192];
    const int tid = threadIdx.x;
    const int lane = tid & 63, w = tid >> 6;
    const int wm = w >> 2, wn = w & 3, kg = lane >> 4, l15 = lane & 15;
    const int m0 = blockIdx.x * 256, n0 = blockIdx.y * 256, z = blockIdx.z;

    const f32x4 z4 = {0.f, 0.f, 0.f, 0.f};
    f32x4 acc[8][4];
    #pragma unroll
    for (int i = 0; i < 8; ++i)
        #pragma unroll
        for (int j = 0; j < 4; ++j) acc[i][j] = z4;

    gemm256(xb, 1024, Wb + (size_t)z * 1048576, 1024, m0, n0, 16, &Ab[0][0], &Bb[0][0], acc);

    if (z < 2) {
        u16* O = (z == 0) ? Qo : Ko;
        #pragma unroll
        for (int mt = 0; mt < 8; ++mt) {
            const int row0 = m0 + wm * 128 + mt * 16 + kg * 4;
            #pragma unroll
            for (int nt = 0; nt < 4; ++nt) {
                const int col = n0 + wn * 64 + nt * 16 + l15;
                #pragma unroll
                for (int r = 0; r < 4; ++r)
                    O[(size_t)(row0 + r) * 1024 + col] = f2bf(acc[mt][nt][r]);
            }
        }
    } else {
        #pragma unroll
        for (int mt = 0; mt < 8; ++mt) {
            const int row0 = m0 + wm * 128 + mt * 16 + kg * 4;
            #pragma unroll
            for (int nt = 0; nt < 4; ++nt) {
                const int col = n0 + wn * 64 + nt * 16 + l15;   // h
                #pragma unroll
                for (int r = 0; r < 4; ++r) {
                    const int rr = row0 + r;
                    VTo[((size_t)(rr >> 11) * 1024 + col) * 2048 + (rr & 2047)] = f2bf(acc[mt][nt][r]);
                }
            }
        }
    }
}

// ---------------------------------------------------------------------------
// 2) S = Q K^T (causal blocks), epilogue P = exp(S/32) masked -> bf16 d_out
// ---------------------------------------------------------------------------
__global__ __launch_bounds__(512, 2) void sp256(
    const u16* __restrict__ Q, const u16* __restrict__ K, u16* __restrict__ P)
{
    const int qb = blockIdx.x, kb = blockIdx.y, b = blockIdx.z;
    if (kb > qb) return;
    __shared__ u16 Ab[4][8192];
    __shared__ u16 Bb[4][8192];
    const int tid = threadIdx.x;
    const int lane = tid & 63, w = tid >> 6;
    const int wm = w >> 2, wn = w & 3, kg = lane >> 4, l15 = lane & 15;

    const f32x4 z4 = {0.f, 0.f, 0.f, 0.f};
    f32x4 acc[8][4];
    #pragma unroll
    for (int i = 0; i < 8; ++i)
        #pragma unroll
        for (int j = 0; j < 4; ++j) acc[i][j] = z4;

    gemm256(Q, 1024, K, 1024, b * 2048 + qb * 256, b * 2048 + kb * 256, 16,
            &Ab[0][0], &Bb[0][0], acc);

    u16* Pb = P + (size_t)b * 2048 * 2048;
    #pragma unroll
    for (int mt = 0; mt < 8; ++mt) {
        const int trow0 = qb * 256 + wm * 128 + mt * 16 + kg * 4;
        #pragma unroll
        for (int nt = 0; nt < 4; ++nt) {
            const int scol = kb * 256 + wn * 64 + nt * 16 + l15;
            #pragma unroll
            for (int r = 0; r < 4; ++r) {
                const int trow = trow0 + r;
                const float p = (scol <= trow) ? __expf(acc[mt][nt][r] * 0.03125f) : 0.f;
                Pb[(size_t)trow * 2048 + scol] = f2bf(p);
            }
        }
    }
}

// ---------------------------------------------------------------------------
// 3) O = P * V^T (unnormalized f32) -> Of.  grid x = b*8+qblk, y = hpanel
// ---------------------------------------------------------------------------
__global__ __launch_bounds__(512, 2) void pv256(
    const u16* __restrict__ P, const u16* __restrict__ VT, float* __restrict__ Of)
{
    const int b = blockIdx.x >> 3, qblk = blockIdx.x & 7;
    const int nb = blockIdx.y;
    const int nk = (qblk + 1) * 4;        // K-tiles of 64 keys
    __shared__ u16 Ab[4][8192];
    __shared__ u16 Bb[4][8192];
    const int tid = threadIdx.x;
    const int lane = tid & 63, w = tid >> 6;
    const int wm = w >> 2, wn = w & 3, kg = lane >> 4, l15 = lane & 15;

    const f32x4 z4 = {0.f, 0.f, 0.f, 0.f};
    f32x4 acc[8][4];
    #pragma unroll
    for (int i = 0; i < 8; ++i)
        #pragma unroll
        for (int j = 0; j < 4; ++j) acc[i][j] = z4;

    gemm256(P + (size_t)b * 2048 * 2048, 2048,
            VT + (size_t)b * 1024 * 2048, 2048,
            qblk * 256, nb * 256, nk, &Ab[0][0], &Bb[0][0], acc);

    #pragma unroll
    for (int mt = 0; mt < 8; ++mt) {
        const int trow0 = qblk * 256 + wm * 128 + mt * 16 + kg * 4;
        #pragma unroll
        for (int nt = 0; nt < 4; ++nt) {
            const int col = nb * 256 + wn * 64 + nt * 16 + l15;
            #pragma unroll
            for (int r = 0; r < 4; ++r)
                Of[((size_t)b * 2048 + trow0 + r) * 1024 + col] = acc[mt][nt][r];
        }
    }
}

// ---------------------------------------------------------------------------
// 4) per row: l = sum(P row), out = Of / l. P row and out row alias exactly.
// ---------------------------------------------------------------------------
__global__ __launch_bounds__(256) void finalize(
    const u16* __restrict__ P, const float* __restrict__ Of, float* __restrict__ out)
{
    const int row = blockIdx.x;           // 0..16383
    const int tid = threadIdx.x;
    const int b = row >> 11, t = row & 2047;
    const int len = ((t >> 8) + 1) * 256;   // written (256-granular) extent
    const u16* prow = P + ((size_t)b * 2048 + t) * 2048;

    float s = 0.f;
    const int i = tid * 8;
    if (i < len) {
        short8 v = *reinterpret_cast<const short8*>(prow + i);
        #pragma unroll
        for (int j = 0; j < 8; ++j) s += bf2f((u16)v[j]);
    }
    #pragma unroll
    for (int d = 1; d < 64; d <<= 1) s += __shfl_xor(s, d, 64);

    __shared__ float red[4];
    if ((tid & 63) == 0) red[tid >> 6] = s;
    __syncthreads();
    const float rinv = 1.f / (red[0] + red[1] + red[2] + red[3]);

    const size_t o = (size_t)row * 1024 + tid * 4;
    f32x4 v = *reinterpret_cast<const f32x4*>(Of + o);
    v[0] *= rinv; v[1] *= rinv; v[2] *= rinv; v[3] *= rinv;
    *reinterpret_cast<f32x4*>(out + o) = v;
}

extern "C" void kernel_launch(void* const* d_in, const int* in_sizes, int n_in,
                              void* d_out, int out_size, void* d_ws, size_t ws_size,
                              hipStream_t stream) {
    const float* x  = (const float*)d_in[0];
    const float* Wq = (const float*)d_in[1];
    const float* Wk = (const float*)d_in[2];
    const float* Wv = (const float*)d_in[3];
    float* out = (float*)d_out;

    // ws: Q[16384][1024] | K[16384][1024] | VT[8][1024][2048]  (bf16, ~100.7MB)
    u16* Qb  = (u16*)d_ws;
    u16* Kb  = Qb + (size_t)16384 * 1024;
    u16* VTb = Kb + (size_t)16384 * 1024;
    float* Of = (float*)d_ws;              // overlays Q,K (dead after sp256)

    // d_out overlays: phase A = xb[16M]+Wb[3M] bf16; phase B = P bf16; final out
    u16* xb = (u16*)d_out;
    u16* Wb = xb + (size_t)16777216;
    u16* Pb = (u16*)d_out;

    cvt_bf16<<<dim3(9728), 256, 0, stream>>>(x, Wq, Wk, Wv, xb);
    qkv256<<<dim3(64, 4, 3), 512, 0, stream>>>(xb, Wb, Qb, Kb, VTb);
    sp256<<<dim3(8, 8, 8), 512, 0, stream>>>(Qb, Kb, Pb);
    pv256<<<dim3(64, 4), 512, 0, stream>>>(Pb, VTb, Of);
    finalize<<<dim3(16384), 256, 0, stream>>>(Pb, Of, out);
}

// Round 4
// 267.234 us; speedup vs baseline: 4.6793x; 1.1218x over previous
//
#include <hip/hip_runtime.h>

typedef unsigned short u16;
typedef short short8 __attribute__((ext_vector_type(8)));
typedef float f32x4 __attribute__((ext_vector_type(4)));

// ---- new-path ws layout (bytes) ----
#define WS_K_OFF    33554432ULL
#define WS_PTRI     67108864ULL
#define WS_PART     104857600ULL
#define WS_RINV     105381888ULL
#define WS_NEED     105447424ULL

__device__ __forceinline__ u16 f2bf(float f) {
    union { float f; unsigned u; } c; c.f = f;
    unsigned r = c.u + 0x7fffu + ((c.u >> 16) & 1u);
    return (u16)(r >> 16);
}
__device__ __forceinline__ float bf2f(u16 h) {
    union { unsigned u; float f; } c; c.u = ((unsigned)h) << 16; return c.f;
}
__device__ __forceinline__ void gll16(const u16* g, u16* l) {
    __builtin_amdgcn_global_load_lds(
        (const __attribute__((address_space(1))) void*)g,
        (__attribute__((address_space(3))) void*)l, 16, 0, 0);
}

// ---------------------------------------------------------------------------
// Pipelined 256x256 NT-GEMM mainloop. BK=32, 8 waves (2Mx4N), quad-buffered
// LDS (4 bufs x (A 16KB + B 16KB) = 128 KiB), staging 3 tiles ahead.
// Steady state at start of body t: buf(t), buf(t+1) landed; stage(t+2) in
// flight. Body t: read frags(t+1) + B(t) while MFMA(t) runs; stage(t+3);
// end: s_waitcnt vmcnt(4); s_barrier.  AMODE==1: A is tile-linear P_tri
// (256x256 tiles of 65536 u16, lda=256), A pre-offset to tile row, m0=0.
// LDS rows are 64 B; 16B-slot swizzle phys = logical ^ ((row>>1)&3)
// (realized by pre-swizzled global source; 2-way bank alias = free).
// ---------------------------------------------------------------------------
template<int AMODE>
__device__ __forceinline__ void gemm_pipe(
    const u16* __restrict__ A, int lda,
    const u16* __restrict__ B, int ldb,
    int m0, int n0, int nk, u16* lds, f32x4 acc[8][4])
{
    const int tid  = threadIdx.x;
    const int lane = tid & 63;
    const int w    = tid >> 6;
    const int wm   = w >> 2, wn = w & 3;
    const int kg   = lane >> 4, l15 = lane & 15;
    const int r0   = w * 32 + (lane >> 2);          // staging row (local)
    const int s0   = (lane & 3) ^ ((r0 >> 1) & 3);  // pre-swizzled k-slot

    const int ldA = AMODE ? 256 : lda;
    const u16* Ar0 = A + (size_t)(m0 + r0) * ldA + s0 * 8;
    const u16* Ar1 = Ar0 + 16 * ldA;
    const u16* Br0 = B + (size_t)(n0 + r0) * ldb + s0 * 8;
    const u16* Br1 = Br0 + 16 * ldb;

    auto aoff = [&](int t) -> int {
        return AMODE ? ((t >> 3) * 65536 + (t & 7) * 32) : t * 32;
    };
    auto STAGE = [&](int t) {
        const int ao = aoff(t), bo = t * 32, buf = (t & 3) * 16384;
        u16* dA = lds + buf + w * 1024;
        u16* dB = lds + buf + 8192 + w * 1024;
        gll16(Ar0 + ao, dA);
        gll16(Ar1 + ao, dA + 512);
        gll16(Br0 + bo, dB);
        gll16(Br1 + bo, dB + 512);
    };
    auto LDA8 = [&](short8* fa, int t) {
        const u16* h = lds + (t & 3) * 16384 + wm * 128 * 32;
        #pragma unroll
        for (int mt = 0; mt < 8; ++mt) {
            const int row = mt * 16 + l15;
            fa[mt] = *reinterpret_cast<const short8*>(
                h + row * 32 + ((kg ^ ((row >> 1) & 3)) << 3));
        }
    };
    auto LDB4 = [&](short8* fb, int t) {
        const u16* h = lds + (t & 3) * 16384 + 8192 + wn * 64 * 32;
        #pragma unroll
        for (int nt = 0; nt < 4; ++nt) {
            const int row = nt * 16 + l15;
            fb[nt] = *reinterpret_cast<const short8*>(
                h + row * 32 + ((kg ^ ((row >> 1) & 3)) << 3));
        }
    };
    auto MFMA32 = [&](short8* fa, short8* fb) {
        __builtin_amdgcn_s_setprio(1);
        #pragma unroll
        for (int mt = 0; mt < 8; ++mt)
            #pragma unroll
            for (int nt = 0; nt < 4; ++nt)
                acc[mt][nt] = __builtin_amdgcn_mfma_f32_16x16x32_bf16(
                    fa[mt], fb[nt], acc[mt][nt], 0, 0, 0);
        __builtin_amdgcn_s_setprio(0);
    };

    // prologue: stage tiles 0,1,2; ensure 0,1 landed (leave 2 in flight)
    STAGE(0); STAGE(1); STAGE(2);
    asm volatile("s_waitcnt vmcnt(4)" ::: "memory");
    __builtin_amdgcn_s_barrier();

    short8 faA[8], faB[8], fb[4];
    LDA8(faA, 0);

    for (int t = 0; t < nk; t += 2) {
        // body t (even): compute with faA, prefetch faB = A(t+1)
        LDB4(fb, t);
        LDA8(faB, t + 1);
        if (t + 3 < nk) STAGE(t + 3);
        MFMA32(faA, fb);
        if (t + 3 < nk) asm volatile("s_waitcnt vmcnt(4)" ::: "memory");
        else            asm volatile("s_waitcnt vmcnt(0)" ::: "memory");
        __builtin_amdgcn_s_barrier();

        // body t+1 (odd): compute with faB, prefetch faA = A(t+2)
        LDB4(fb, t + 1);
        if (t + 2 < nk) LDA8(faA, t + 2);
        if (t + 4 < nk) STAGE(t + 4);
        MFMA32(faB, fb);
        if (t + 4 < nk) asm volatile("s_waitcnt vmcnt(4)" ::: "memory");
        else            asm volatile("s_waitcnt vmcnt(0)" ::: "memory");
        __builtin_amdgcn_s_barrier();
    }
}

// ---------------------------------------------------------------------------
// 0) cast x and Wq/Wk/Wv to bf16 into d_out: xb[16M] then Wb[3][1M]
// ---------------------------------------------------------------------------
__global__ __launch_bounds__(256) void cvt_bf16(
    const float* __restrict__ x,
    const float* __restrict__ Wq,
    const float* __restrict__ Wk,
    const float* __restrict__ Wv,
    u16* __restrict__ dst)
{
    const size_t e = ((size_t)blockIdx.x * 256 + threadIdx.x) * 8;
    const float* src;
    if (e < (size_t)16777216) {
        src = x + e;
    } else {
        size_t j = e - 16777216;
        int z = (int)(j >> 20);
        const float* Wz = (z == 0) ? Wq : (z == 1) ? Wk : Wv;
        src = Wz + (j & 1048575);
    }
    float4 a = *reinterpret_cast<const float4*>(src);
    float4 b = *reinterpret_cast<const float4*>(src + 4);
    short8 v;
    v[0] = (short)f2bf(a.x); v[1] = (short)f2bf(a.y);
    v[2] = (short)f2bf(a.z); v[3] = (short)f2bf(a.w);
    v[4] = (short)f2bf(b.x); v[5] = (short)f2bf(b.y);
    v[6] = (short)f2bf(b.z); v[7] = (short)f2bf(b.w);
    *reinterpret_cast<short8*>(dst + e) = v;
}

// ---------------------------------------------------------------------------
// 1) QKV projection. z = blockIdx.z + zbase: 0 -> Q, 1 -> K, 2 -> V^T[b][h][t]
// ---------------------------------------------------------------------------
__global__ __launch_bounds__(512, 2) void qkv_pipe(
    const u16* __restrict__ xb, const u16* __restrict__ Wb,
    u16* __restrict__ Qo, u16* __restrict__ Ko, u16* __restrict__ VTo, int zbase)
{
    __shared__ u16 L[65536];
    const int tid = threadIdx.x, lane = tid & 63, w = tid >> 6;
    const int wm = w >> 2, wn = w & 3, kg = lane >> 4, l15 = lane & 15;
    const int m0 = blockIdx.x * 256, n0 = blockIdx.y * 256;
    const int z = blockIdx.z + zbase;

    const f32x4 z4 = {0.f, 0.f, 0.f, 0.f};
    f32x4 acc[8][4];
    #pragma unroll
    for (int i = 0; i < 8; ++i)
        #pragma unroll
        for (int j = 0; j < 4; ++j) acc[i][j] = z4;

    gemm_pipe<0>(xb, 1024, Wb + (size_t)z * 1048576, 1024, m0, n0, 32, L, acc);

    if (z < 2) {
        u16* O = (z == 0) ? Qo : Ko;
        #pragma unroll
        for (int mt = 0; mt < 8; ++mt) {
            const int row0 = m0 + wm * 128 + mt * 16 + kg * 4;
            #pragma unroll
            for (int nt = 0; nt < 4; ++nt) {
                const int col = n0 + wn * 64 + nt * 16 + l15;
                #pragma unroll
                for (int r = 0; r < 4; ++r)
                    O[(size_t)(row0 + r) * 1024 + col] = f2bf(acc[mt][nt][r]);
            }
        }
    } else {
        #pragma unroll
        for (int mt = 0; mt < 8; ++mt) {
            const int row0 = m0 + wm * 128 + mt * 16 + kg * 4;
            #pragma unroll
            for (int nt = 0; nt < 4; ++nt) {
                const int col = n0 + wn * 64 + nt * 16 + l15;   // h
                #pragma unroll
                for (int r = 0; r < 4; ++r) {
                    const int rr = row0 + r;
                    VTo[((size_t)(rr >> 11) * 1024 + col) * 2048 + (rr & 2047)] = f2bf(acc[mt][nt][r]);
                }
            }
        }
    }
}

// ---------------------------------------------------------------------------
// 2a) NEW: S -> P=exp(S/32) masked -> P_tri tile + per-block row partials
// ---------------------------------------------------------------------------
__global__ __launch_bounds__(512, 2) void sp_new(
    const u16* __restrict__ Q, const u16* __restrict__ K,
    u16* __restrict__ Ptri, float* __restrict__ partials)
{
    const int qb = blockIdx.x, kb = blockIdx.y, b = blockIdx.z;
    if (kb > qb) return;
    __shared__ u16 L[65536];
    const int tid = threadIdx.x, lane = tid & 63, w = tid >> 6;
    const int wm = w >> 2, wn = w & 3, kg = lane >> 4, l15 = lane & 15;

    const f32x4 z4 = {0.f, 0.f, 0.f, 0.f};
    f32x4 acc[8][4];
    #pragma unroll
    for (int i = 0; i < 8; ++i)
        #pragma unroll
        for (int j = 0; j < 4; ++j) acc[i][j] = z4;

    gemm_pipe<0>(Q, 1024, K, 1024, b * 2048 + qb * 256, b * 2048 + kb * 256, 32, L, acc);

    u16* Pt = Ptri + ((size_t)b * 36 + (qb * (qb + 1)) / 2 + kb) * 65536;
    float* psum = (float*)L;    // [256][4] — LDS free after mainloop barrier
    #pragma unroll
    for (int mt = 0; mt < 8; ++mt) {
        const int lt0 = wm * 128 + mt * 16 + kg * 4;
        #pragma unroll
        for (int r = 0; r < 4; ++r) {
            const int lt = lt0 + r;
            const int gt = qb * 256 + lt;
            float ps = 0.f;
            #pragma unroll
            for (int nt = 0; nt < 4; ++nt) {
                const int lcol = wn * 64 + nt * 16 + l15;
                const int gs = kb * 256 + lcol;
                const float p = (gs <= gt) ? __expf(acc[mt][nt][r] * 0.03125f) : 0.f;
                ps += p;
                Pt[(size_t)lt * 256 + lcol] = f2bf(p);
            }
            #pragma unroll
            for (int d = 1; d < 16; d <<= 1) ps += __shfl_xor(ps, d, 64);
            if (l15 == 0) psum[lt * 4 + wn] = ps;
        }
    }
    __syncthreads();
    if (tid < 256) {
        const float s = psum[tid * 4] + psum[tid * 4 + 1] + psum[tid * 4 + 2] + psum[tid * 4 + 3];
        partials[((size_t)b * 2048 + qb * 256 + tid) * 8 + kb] = s;
    }
}

// 2b) OLD: full-square P in d_out (round-3 semantics)
__global__ __launch_bounds__(512, 2) void sp_old(
    const u16* __restrict__ Q, const u16* __restrict__ K, u16* __restrict__ P)
{
    const int qb = blockIdx.x, kb = blockIdx.y, b = blockIdx.z;
    if (kb > qb) return;
    __shared__ u16 L[65536];
    const int tid = threadIdx.x, lane = tid & 63, w = tid >> 6;
    const int wm = w >> 2, wn = w & 3, kg = lane >> 4, l15 = lane & 15;

    const f32x4 z4 = {0.f, 0.f, 0.f, 0.f};
    f32x4 acc[8][4];
    #pragma unroll
    for (int i = 0; i < 8; ++i)
        #pragma unroll
        for (int j = 0; j < 4; ++j) acc[i][j] = z4;

    gemm_pipe<0>(Q, 1024, K, 1024, b * 2048 + qb * 256, b * 2048 + kb * 256, 32, L, acc);

    u16* Pb = P + (size_t)b * 2048 * 2048;
    #pragma unroll
    for (int mt = 0; mt < 8; ++mt) {
        const int trow0 = qb * 256 + wm * 128 + mt * 16 + kg * 4;
        #pragma unroll
        for (int nt = 0; nt < 4; ++nt) {
            const int scol = kb * 256 + wn * 64 + nt * 16 + l15;
            #pragma unroll
            for (int r = 0; r < 4; ++r) {
                const int trow = trow0 + r;
                const float p = (scol <= trow) ? __expf(acc[mt][nt][r] * 0.03125f) : 0.f;
                Pb[(size_t)trow * 2048 + scol] = f2bf(p);
            }
        }
    }
}

// ---------------------------------------------------------------------------
// 3) rowsum (new path): rinv[row] = 1 / sum_kb partials[row][kb]
// ---------------------------------------------------------------------------
__global__ __launch_bounds__(256) void rowsum_k(
    const float* __restrict__ partials, float* __restrict__ rinv)
{
    const int row = blockIdx.x * 256 + threadIdx.x;
    const int qb = (row & 2047) >> 8;
    float s = 0.f;
    for (int kb = 0; kb <= qb; ++kb) s += partials[(size_t)row * 8 + kb];
    rinv[row] = 1.f / s;
}

// ---------------------------------------------------------------------------
// 4a) NEW: O = (P_tri * V^T) * rinv -> d_out f32 directly
// ---------------------------------------------------------------------------
__global__ __launch_bounds__(512, 2) void pv_new(
    const u16* __restrict__ Ptri, const u16* __restrict__ VT,
    const float* __restrict__ rinv, float* __restrict__ out)
{
    const int b = blockIdx.x >> 3, qblk = blockIdx.x & 7;
    const int nb = blockIdx.y;
    const int nk = (qblk + 1) * 8;
    __shared__ u16 L[65536];
    const int tid = threadIdx.x, lane = tid & 63, w = tid >> 6;
    const int wm = w >> 2, wn = w & 3, kg = lane >> 4, l15 = lane & 15;

    const f32x4 z4 = {0.f, 0.f, 0.f, 0.f};
    f32x4 acc[8][4];
    #pragma unroll
    for (int i = 0; i < 8; ++i)
        #pragma unroll
        for (int j = 0; j < 4; ++j) acc[i][j] = z4;

    const u16* Aq = Ptri + ((size_t)b * 36 + (qblk * (qblk + 1)) / 2) * 65536;
    gemm_pipe<1>(Aq, 256, VT + (size_t)b * 1024 * 2048, 2048, 0, nb * 256, nk, L, acc);

    #pragma unroll
    for (int mt = 0; mt < 8; ++mt) {
        const int lt0 = wm * 128 + mt * 16 + kg * 4;
        const int grow0 = b * 2048 + qblk * 256 + lt0;
        float rs[4];
        #pragma unroll
        for (int r = 0; r < 4; ++r) rs[r] = rinv[grow0 + r];
        #pragma unroll
        for (int nt = 0; nt < 4; ++nt) {
            const int col = nb * 256 + wn * 64 + nt * 16 + l15;
            #pragma unroll
            for (int r = 0; r < 4; ++r)
                out[(size_t)(grow0 + r) * 1024 + col] = acc[mt][nt][r] * rs[r];
        }
    }
}

// 4b) OLD: O = P * V^T (unnormalized f32) -> Of in ws
__global__ __launch_bounds__(512, 2) void pv_old(
    const u16* __restrict__ P, const u16* __restrict__ VT, float* __restrict__ Of)
{
    const int b = blockIdx.x >> 3, qblk = blockIdx.x & 7;
    const int nb = blockIdx.y;
    const int nk = (qblk + 1) * 8;
    __shared__ u16 L[65536];
    const int tid = threadIdx.x, lane = tid & 63, w = tid >> 6;
    const int wm = w >> 2, wn = w & 3, kg = lane >> 4, l15 = lane & 15;

    const f32x4 z4 = {0.f, 0.f, 0.f, 0.f};
    f32x4 acc[8][4];
    #pragma unroll
    for (int i = 0; i < 8; ++i)
        #pragma unroll
        for (int j = 0; j < 4; ++j) acc[i][j] = z4;

    gemm_pipe<0>(P + (size_t)b * 2048 * 2048, 2048,
                 VT + (size_t)b * 1024 * 2048, 2048,
                 qblk * 256, nb * 256, nk, L, acc);

    #pragma unroll
    for (int mt = 0; mt < 8; ++mt) {
        const int trow0 = qblk * 256 + wm * 128 + mt * 16 + kg * 4;
        #pragma unroll
        for (int nt = 0; nt < 4; ++nt) {
            const int col = nb * 256 + wn * 64 + nt * 16 + l15;
            #pragma unroll
            for (int r = 0; r < 4; ++r)
                Of[((size_t)b * 2048 + trow0 + r) * 1024 + col] = acc[mt][nt][r];
        }
    }
}

// 5) OLD: per row l = sum(P row); out = Of / l (P row and out row alias)
__global__ __launch_bounds__(256) void finalize(
    const u16* __restrict__ P, const float* __restrict__ Of, float* __restrict__ out)
{
    const int row = blockIdx.x;
    const int tid = threadIdx.x;
    const int b = row >> 11, t = row & 2047;
    const int len = ((t >> 8) + 1) * 256;
    const u16* prow = P + ((size_t)b * 2048 + t) * 2048;

    float s = 0.f;
    const int i = tid * 8;
    if (i < len) {
        short8 v = *reinterpret_cast<const short8*>(prow + i);
        #pragma unroll
        for (int j = 0; j < 8; ++j) s += bf2f((u16)v[j]);
    }
    #pragma unroll
    for (int d = 1; d < 64; d <<= 1) s += __shfl_xor(s, d, 64);

    __shared__ float red[4];
    if ((tid & 63) == 0) red[tid >> 6] = s;
    __syncthreads();
    const float rinv = 1.f / (red[0] + red[1] + red[2] + red[3]);

    const size_t o = (size_t)row * 1024 + tid * 4;
    f32x4 v = *reinterpret_cast<const f32x4*>(Of + o);
    v[0] *= rinv; v[1] *= rinv; v[2] *= rinv; v[3] *= rinv;
    *reinterpret_cast<f32x4*>(out + o) = v;
}

extern "C" void kernel_launch(void* const* d_in, const int* in_sizes, int n_in,
                              void* d_out, int out_size, void* d_ws, size_t ws_size,
                              hipStream_t stream) {
    const float* x  = (const float*)d_in[0];
    const float* Wq = (const float*)d_in[1];
    const float* Wk = (const float*)d_in[2];
    const float* Wv = (const float*)d_in[3];

    // d_out overlays: phase A = xb[16M]+Wb[3M] bf16; final = out f32
    u16* xb = (u16*)d_out;
    u16* Wb = xb + (size_t)16777216;

    cvt_bf16<<<dim3(9728), 256, 0, stream>>>(x, Wq, Wk, Wv, xb);

    if (ws_size >= WS_NEED) {
        // NEW: ws = Q | K | P_tri | partials | rinv ; VT overwrites Q after sp
        u16*   Qb   = (u16*)d_ws;
        u16*   Kb   = (u16*)((char*)d_ws + WS_K_OFF);
        u16*   Pt   = (u16*)((char*)d_ws + WS_PTRI);
        float* part = (float*)((char*)d_ws + WS_PART);
        float* rinv = (float*)((char*)d_ws + WS_RINV);
        u16*   VTb  = Qb;   // Q dead after sp_new

        qkv_pipe<<<dim3(64, 4, 2), 512, 0, stream>>>(xb, Wb, Qb, Kb, Qb, 0);
        sp_new<<<dim3(8, 8, 8), 512, 0, stream>>>(Qb, Kb, Pt, part);
        rowsum_k<<<dim3(64), 256, 0, stream>>>(part, rinv);
        qkv_pipe<<<dim3(64, 4, 1), 512, 0, stream>>>(xb, Wb, Qb, Kb, VTb, 2);
        pv_new<<<dim3(64, 4), 512, 0, stream>>>(Pt, VTb, rinv, (float*)d_out);
    } else {
        // OLD (round-3 dataflow): ws = Q | K | VT ; P in d_out; Of over Q/K
        u16* Qb  = (u16*)d_ws;
        u16* Kb  = Qb + (size_t)16384 * 1024;
        u16* VTb = Kb + (size_t)16384 * 1024;
        float* Of = (float*)d_ws;
        u16* Pb = (u16*)d_out;

        qkv_pipe<<<dim3(64, 4, 3), 512, 0, stream>>>(xb, Wb, Qb, Kb, VTb, 0);
        sp_old<<<dim3(8, 8, 8), 512, 0, stream>>>(Qb, Kb, Pb);
        pv_old<<<dim3(64, 4), 512, 0, stream>>>(Pb, VTb, Of);
        finalize<<<dim3(16384), 256, 0, stream>>>(Pb, Of, (float*)d_out);
    }
}